// Round 1
// baseline (861.690 us; speedup 1.0000x reference)
//
#include <hip/hip_runtime.h>
#include <hip/hip_bf16.h>

#define RNUM 8
#define HH1 32
#define HH2 16
#define FIN 128
#define NPB 16

__global__ __launch_bounds__(256) void k_count(const int* __restrict__ ei,
    const int* __restrict__ ea, int* __restrict__ cnt, int E) {
  int e = blockIdx.x * 256 + threadIdx.x;
  if (e < E) {
    atomicAdd(&cnt[ei[E + e] * RNUM + ea[e]], 1);
  }
}

__global__ __launch_bounds__(256) void k_inv(const int* __restrict__ cnt,
    float* __restrict__ invc, int n) {
  int i = blockIdx.x * 256 + threadIdx.x;
  if (i < n) {
    int c = cnt[i];
    invc[i] = 1.0f / (float)(c > 1 ? c : 1);
  }
}

// xw1[n][r*32+h] = sum_i x[n][i] * W1[r][i][h]; agg1[n][h] = sum_i x[n][i]*root1[i][h] + b1[h]
__global__ __launch_bounds__(256) void k_gemm1(const float* __restrict__ x,
    const float* __restrict__ W, const float* __restrict__ root,
    const float* __restrict__ b, float* __restrict__ xw,
    float* __restrict__ agg, int N) {
  __shared__ float xs[NPB][FIN];
  int n0 = blockIdx.x * NPB;
  int t = threadIdx.x;
  #pragma unroll
  for (int rep = 0; rep < 2; ++rep) {
    int q = t + rep * 256;
    int n = q >> 5;            // 32 float4 per node row
    int i0 = (q & 31) << 2;
    int nn = n0 + n;
    float4 v = make_float4(0.f, 0.f, 0.f, 0.f);
    if (nn < N) v = *(const float4*)(x + (size_t)nn * FIN + i0);
    *(float4*)(&xs[n][i0]) = v;
  }
  __syncthreads();

  // W part: thread t owns column c=t (r=t>>5, h=t&31) for all NPB nodes
  float acc[NPB];
  #pragma unroll
  for (int n = 0; n < NPB; ++n) acc[n] = 0.f;
  const float* Wc = W + ((t >> 5) * FIN * HH1) + (t & 31);
  #pragma unroll 4
  for (int i = 0; i < FIN; ++i) {
    float w = Wc[(size_t)i * HH1];
    #pragma unroll
    for (int n = 0; n < NPB; ++n) acc[n] = fmaf(w, xs[n][i], acc[n]);
  }
  #pragma unroll
  for (int n = 0; n < NPB; ++n) {
    int nn = n0 + n;
    if (nn < N) xw[(size_t)nn * (RNUM * HH1) + t] = acc[n];
  }

  // root part: 32 cols x 16 nodes = 512 outputs, 2 per thread
  int c = t & 31;
  int nr = t >> 5;  // 0..7
  float r0 = 0.f, r1 = 0.f;
  const float* Rc = root + c;
  #pragma unroll 4
  for (int i = 0; i < FIN; ++i) {
    float w = Rc[(size_t)i * HH1];
    r0 = fmaf(w, xs[nr][i], r0);
    r1 = fmaf(w, xs[nr + 8][i], r1);
  }
  float bb = b[c];
  int nn0 = n0 + nr, nn1 = n0 + nr + 8;
  if (nn0 < N) agg[(size_t)nn0 * HH1 + c] = r0 + bb;
  if (nn1 < N) agg[(size_t)nn1 * HH1 + c] = r1 + bb;
}

__global__ __launch_bounds__(256) void k_edge1(const int* __restrict__ ei,
    const int* __restrict__ ea, const float* __restrict__ invc,
    const float* __restrict__ xw, float* __restrict__ agg, int E) {
  int gid = blockIdx.x * 256 + threadIdx.x;
  int e = gid >> 5;
  if (e < E) {
    int h = gid & 31;
    int src = ei[e], dst = ei[E + e], rel = ea[e];
    float w = invc[dst * RNUM + rel];
    float v = xw[((size_t)src * RNUM + rel) * HH1 + h];
    atomicAdd(&agg[(size_t)dst * HH1 + h], w * v);
  }
}

// reads relu(agg1) on the fly; xw2[n][r*16+h] = h1 @ W2; agg2 = h1 @ root2 + b2
__global__ __launch_bounds__(256) void k_gemm2(const float* __restrict__ agg1,
    const float* __restrict__ W, const float* __restrict__ root,
    const float* __restrict__ b, float* __restrict__ xw,
    float* __restrict__ agg, int N) {
  __shared__ float hs[NPB][HH1];
  int n0 = blockIdx.x * NPB;
  int t = threadIdx.x;
  {
    int n = t >> 4;
    int i0 = (t & 15) << 1;
    int nn = n0 + n;
    float2 v = make_float2(0.f, 0.f);
    if (nn < N) v = *(const float2*)(agg1 + (size_t)nn * HH1 + i0);
    hs[n][i0] = fmaxf(v.x, 0.f);
    hs[n][i0 + 1] = fmaxf(v.y, 0.f);
  }
  __syncthreads();

  int c = t & 127;         // r = c>>4, h = c&15
  int ns = t >> 7;         // 0 or 1
  const float* Wc = W + ((c >> 4) * HH1 * HH2) + (c & 15);
  float acc[8];
  #pragma unroll
  for (int k = 0; k < 8; ++k) acc[k] = 0.f;
  #pragma unroll 4
  for (int i = 0; i < HH1; ++i) {
    float w = Wc[(size_t)i * HH2];
    #pragma unroll
    for (int k = 0; k < 8; ++k) acc[k] = fmaf(w, hs[ns + 2 * k][i], acc[k]);
  }
  #pragma unroll
  for (int k = 0; k < 8; ++k) {
    int nn = n0 + ns + 2 * k;
    if (nn < N) xw[(size_t)nn * (RNUM * HH2) + c] = acc[k];
  }

  // root part: 16 cols x 16 nodes = 256 outputs, 1 per thread
  int c2 = t & 15;
  int n = t >> 4;
  float r0 = 0.f;
  const float* Rc = root + c2;
  #pragma unroll 4
  for (int i = 0; i < HH1; ++i) r0 = fmaf(Rc[(size_t)i * HH2], hs[n][i], r0);
  int nn = n0 + n;
  if (nn < N) agg[(size_t)nn * HH2 + c2] = r0 + b[c2];
}

__global__ __launch_bounds__(256) void k_edge2(const int* __restrict__ ei,
    const int* __restrict__ ea, const float* __restrict__ invc,
    const float* __restrict__ xw, float* __restrict__ agg, int E) {
  int gid = blockIdx.x * 256 + threadIdx.x;
  int e = gid >> 4;
  if (e < E) {
    int h = gid & 15;
    int src = ei[e], dst = ei[E + e], rel = ea[e];
    float w = invc[dst * RNUM + rel];
    float v = xw[((size_t)src * RNUM + rel) * HH2 + h];
    atomicAdd(&agg[(size_t)dst * HH2 + h], w * v);
  }
}

__global__ __launch_bounds__(256) void k_pool(const float* __restrict__ agg2,
    const int* __restrict__ batch, unsigned* __restrict__ pooled, int N) {
  int gid = blockIdx.x * 256 + threadIdx.x;
  int n = gid >> 4;
  if (n < N) {
    int h = gid & 15;
    float v = fmaxf(agg2[(size_t)n * HH2 + h], 0.f);
    // v >= 0 so uint bit pattern is order-preserving; pooled pre-zeroed
    atomicMax(&pooled[batch[n] * HH2 + h], __float_as_uint(v));
  }
}

__global__ __launch_bounds__(256) void k_dense(const float* __restrict__ pooled,
    const float* __restrict__ dw, const float* __restrict__ db,
    float* __restrict__ out, int Gn) {
  int g = blockIdx.x * 256 + threadIdx.x;
  if (g < Gn) {
    float s = db[0];
    #pragma unroll
    for (int h = 0; h < HH2; ++h) s += pooled[(size_t)g * HH2 + h] * dw[h];
    out[g] = s;
  }
}

extern "C" void kernel_launch(void* const* d_in, const int* in_sizes, int n_in,
                              void* d_out, int out_size, void* d_ws, size_t ws_size,
                              hipStream_t stream) {
  const float* x     = (const float*)d_in[0];
  const int*   ei    = (const int*)d_in[1];
  const int*   ea    = (const int*)d_in[2];
  const int*   batch = (const int*)d_in[3];
  const float* W1    = (const float*)d_in[4];
  const float* root1 = (const float*)d_in[5];
  const float* b1    = (const float*)d_in[6];
  const float* W2    = (const float*)d_in[7];
  const float* root2 = (const float*)d_in[8];
  const float* b2    = (const float*)d_in[9];
  const float* dw    = (const float*)d_in[10];
  const float* db    = (const float*)d_in[11];
  float* out = (float*)d_out;

  const int N  = in_sizes[0] / FIN;
  const int E  = in_sizes[2];
  const int Gn = out_size;

  char* ws = (char*)d_ws;
  size_t off = 0;
  auto walloc = [&](size_t bytes) -> void* {
    void* p = (void*)(ws + off);
    off += (bytes + 255) & ~(size_t)255;
    return p;
  };
  int*      cnt    = (int*)     walloc((size_t)N * RNUM * 4);
  float*    invc   = (float*)   walloc((size_t)N * RNUM * 4);
  float*    xw1    = (float*)   walloc((size_t)N * RNUM * HH1 * 4);
  float*    agg1   = (float*)   walloc((size_t)N * HH1 * 4);
  float*    xw2    = (float*)   walloc((size_t)N * RNUM * HH2 * 4);
  float*    agg2   = (float*)   walloc((size_t)N * HH2 * 4);
  unsigned* pooled = (unsigned*)walloc((size_t)Gn * HH2 * 4);

  hipMemsetAsync(cnt, 0, (size_t)N * RNUM * 4, stream);
  hipMemsetAsync(pooled, 0, (size_t)Gn * HH2 * 4, stream);

  k_count<<<(E + 255) / 256, 256, 0, stream>>>(ei, ea, cnt, E);
  k_inv<<<(N * RNUM + 255) / 256, 256, 0, stream>>>(cnt, invc, N * RNUM);
  k_gemm1<<<(N + NPB - 1) / NPB, 256, 0, stream>>>(x, W1, root1, b1, xw1, agg1, N);
  {
    long tot = (long)E * HH1;
    k_edge1<<<(int)((tot + 255) / 256), 256, 0, stream>>>(ei, ea, invc, xw1, agg1, E);
  }
  k_gemm2<<<(N + NPB - 1) / NPB, 256, 0, stream>>>(agg1, W2, root2, b2, xw2, agg2, N);
  {
    long tot = (long)E * HH2;
    k_edge2<<<(int)((tot + 255) / 256), 256, 0, stream>>>(ei, ea, invc, xw2, agg2, E);
  }
  k_pool<<<(int)(((long)N * HH2 + 255) / 256), 256, 0, stream>>>(agg2, batch, pooled, N);
  k_dense<<<(Gn + 255) / 256, 256, 0, stream>>>((const float*)pooled, dw, db, out, Gn);
}